// Round 10
// baseline (261.599 us; speedup 1.0000x reference)
//
#include <hip/hip_runtime.h>
#include <hip/hip_bf16.h>

#define NB 16384
#define DIM 32
#define LS 100
#define KH 50
#define PCOLS 9696           // 3*DIM*LS + 3*DIM
#define LPAD 112             // LS padded to 7*16
#define DSTRIDE 352          // 3*LPAD + 16 tail slots (bias2, eps, alpha, 13 zero)
#define NCR (DIM * DSTRIDE)  // 11264 reordered columns
#define KPAD 64              // 50 real + 1 bias row + 13 zero
#define PREPB (NCR / 64)     // 176 prep blocks per subnet
#define HB1B (NB * 64 / 256) // 4096 h-blocks
#define XTB (NB / 64)        // 256 x-transpose blocks

typedef __attribute__((ext_vector_type(4))) float f32x4;
typedef __attribute__((ext_vector_type(8))) short short8;

static __device__ __forceinline__ unsigned short f2bf(float f) {
    __hip_bfloat16 h = __float2bfloat16(f);
    return *reinterpret_cast<unsigned short*>(&h);
}
static __device__ __forceinline__ float bf2f(unsigned short u) {
    __hip_bfloat16 h = *reinterpret_cast<__hip_bfloat16*>(&u);
    return __bfloat162float(h);
}

// ---- reorder + pad + bf16-ify W2 (b2 folded as k=50 row), linear k layout ----
// W2R[row][k], row = d*352 + q; q<336: q=t*112+l (orig col t*3200+d*100+l);
// q in 336..338: tail cols 9600/9632/9664 + d (bias2, eps, alpha); rest zero.
static __device__ __forceinline__ void prep_body(int bx, const float* __restrict__ W2,
                                                 const float* __restrict__ b2,
                                                 unsigned short* __restrict__ W2R,
                                                 float* lds) {
    unsigned short (&tile)[64][66] = *reinterpret_cast<unsigned short (*)[64][66]>(lds);
    int cb = bx * 64;
    int tid = threadIdx.x;
    int cl = tid & 63;
    int kg = tid >> 6;
    int cp = cb + cl;
    int d = cp / DSTRIDE;
    int q = cp - d * DSTRIDE;
    int col;
    bool valid;
    if (q < 3 * LPAD) {
        int t = q / LPAD;
        int l = q - t * LPAD;
        col = t * (DIM * LS) + d * LS + l;
        valid = (l < LS);
    } else {
        int e = q - 3 * LPAD;
        col = 3 * DIM * LS + e * DIM + d;
        valid = (e < 3);
    }
#pragma unroll
    for (int kk = 0; kk < 16; kk++) {
        int k = kg * 16 + kk;
        float v = 0.0f;
        if (valid) {
            if (k < KH)       v = W2[(size_t)k * PCOLS + col];
            else if (k == KH) v = b2[col];
        }
        tile[cl][k] = f2bf(v);
    }
    __syncthreads();
    int k = tid & 63;
    int cg = tid >> 6;
#pragma unroll
    for (int ii = 0; ii < 16; ii++) {
        int lr = cg * 16 + ii;
        W2R[(size_t)(cb + lr) * KPAD + k] = tile[lr][k];
    }
}

// ---- h = relu(cond @ W1 + b1) -> bf16 [NB][64]; h[50]=1 (bias hook) ----
static __device__ __forceinline__ void h_body(int bx, const float* __restrict__ cond,
                                              int cond_off, const float* __restrict__ W1,
                                              const float* __restrict__ b1,
                                              unsigned short* __restrict__ hb) {
    int idx = bx * 256 + threadIdx.x;   // = s*64 + k; s is wave-uniform
    int s = idx >> 6, k = idx & 63;
    float v;
    if (k < KH) {
        const float* crow = cond + (size_t)s * 64 + cond_off;
        float acc = b1[k];
#pragma unroll
        for (int j = 0; j < DIM; j++) acc = fmaf(crow[j], W1[j * KH + k], acc);
        v = fmaxf(acc, 0.0f);
    } else {
        v = (k == KH) ? 1.0f : 0.0f;
    }
    hb[idx] = f2bf(v);
}

// ---- xT[c][s] = x[s][c]: LDS tile transpose, both sides coalesced ----
static __device__ __forceinline__ void xt_body(int bx, const float* __restrict__ x,
                                               float* __restrict__ xT, float* lds) {
    float (&tile)[64][65] = *reinterpret_cast<float (*)[64][65]>(lds);
    int sb = bx * 64;
    int tid = threadIdx.x;
#pragma unroll
    for (int i = 0; i < 16; i++) {
        int idx = i * 256 + tid;
        int sl = idx >> 6, c = idx & 63;
        tile[c][sl] = x[(size_t)(sb + sl) * 64 + c];
    }
    __syncthreads();
#pragma unroll
    for (int i = 0; i < 16; i++) {
        int idx = i * 256 + tid;
        int c = idx >> 6, sl = idx & 63;
        xT[(size_t)c * NB + sb + sl] = tile[c][sl];
    }
}

// ---- combined: prep both subnets' W2R + h1 + x-transpose (all independent) ----
__global__ __launch_bounds__(256) void combo_kernel(const float* __restrict__ W2a,
                                                    const float* __restrict__ b2a,
                                                    unsigned short* __restrict__ W2Ra,
                                                    const float* __restrict__ W2b,
                                                    const float* __restrict__ b2b,
                                                    unsigned short* __restrict__ W2Rb,
                                                    const float* __restrict__ x,
                                                    const float* __restrict__ W1,
                                                    const float* __restrict__ b1,
                                                    unsigned short* __restrict__ hb,
                                                    float* __restrict__ xT) {
    __shared__ float lds[64 * 65];
    int b = blockIdx.x;
    if (b < PREPB)                 prep_body(b, W2a, b2a, W2Ra, lds);
    else if (b < 2 * PREPB)        prep_body(b - PREPB, W2b, b2b, W2Rb, lds);
    else if (b < 2 * PREPB + HB1B) h_body(b - 2 * PREPB, x, DIM, W1, b1, hb);
    else                           xt_body(b - 2 * PREPB - HB1B, x, xT, lds);
}

__global__ __launch_bounds__(256) void h_kernel(const float* __restrict__ cond, int cond_off,
                                                const float* __restrict__ W1,
                                                const float* __restrict__ b1,
                                                unsigned short* __restrict__ hb) {
    h_body(blockIdx.x, cond, cond_off, W1, b1, hb);
}

// ---- tail params from W2R's k-major tail rows (wave-uniform weights) ----
// thread t = d*NB + s; outputs [d][s]-coalesced.
__global__ __launch_bounds__(256) void tail_kernel(const unsigned short* __restrict__ hb,
                                                   const unsigned short* __restrict__ W2R,
                                                   float* __restrict__ tB,
                                                   float* __restrict__ tS,
                                                   float* __restrict__ tA) {
    int t = blockIdx.x * 256 + threadIdx.x;
    int d = t >> 14;            // NB = 16384
    int s = t & (NB - 1);
    const unsigned short* hrow = hb + (size_t)s * KPAD;
    const unsigned short* wb = W2R + ((size_t)d * DSTRIDE + 3 * LPAD) * KPAD;
    float pb = 0.f, pe = 0.f, pa = 0.f;
#pragma unroll
    for (int k = 0; k <= KH; k++) {      // k=50 carries b2 (h[50]=1)
        float hk = bf2f(hrow[k]);
        pb = fmaf(hk, bf2f(wb[k]), pb);
        pe = fmaf(hk, bf2f(wb[KPAD + k]), pe);
        pa = fmaf(hk, bf2f(wb[2 * KPAD + k]), pa);
    }
    int idx = d * NB + s;
    tB[idx] = pb;
    tS[idx] = 0.8f / (1.0f + __expf(-pe * 0.1f));
    tA[idx] = __expf(pa * 0.1f);
}

// ---- fused p-GEMM (MFMA, B from L2 w/ 2-deep reg prefetch) + PfndELU epilogue ----
// 256-thread block = 4 waves sharing one d; each wave: 64 samples (MT=4).
// Exact R3 register structure (108 VGPR): no in-kernel tail MFMA.
__global__ __launch_bounds__(256) void y_mfma(const float* __restrict__ xT, int xt_off,
                                              const unsigned short* __restrict__ hb,
                                              const unsigned short* __restrict__ W2R,
                                              const float* __restrict__ tB,
                                              const float* __restrict__ tS,
                                              const float* __restrict__ tA,
                                              float* __restrict__ out, int out_off) {
    int tid = threadIdx.x;
    int lane = tid & 63, wave = tid >> 6;
    int c = lane & 15, g = lane >> 4;
    int d = blockIdx.y;
    int m0 = (blockIdx.x * 4 + wave) * 64;

    short8 af[4][2];
#pragma unroll
    for (int mt = 0; mt < 4; mt++)
#pragma unroll
        for (int ks = 0; ks < 2; ks++)
            af[mt][ks] = *reinterpret_cast<const short8*>(
                hb + (size_t)(m0 + mt * 16 + c) * KPAD + ks * 32 + g * 8);

    const float* xrow = xT + (size_t)(xt_off + d) * NB + m0;
    float xv[4][4];
#pragma unroll
    for (int mt = 0; mt < 4; mt++)
#pragma unroll
        for (int r = 0; r < 4; r++)
            xv[mt][r] = xrow[mt * 16 + g * 4 + r];

    float num[4][4] = {};
    float den[4][4] = {};
    const unsigned short* wbase = W2R + (size_t)d * DSTRIDE * KPAD;

    short8 bfA[3][2], bfB[3][2];
    auto loadB = [&](short8 (&dst)[3][2], int j) {
#pragma unroll
        for (int t = 0; t < 3; t++)
#pragma unroll
            for (int ks = 0; ks < 2; ks++)
                dst[t][ks] = *reinterpret_cast<const short8*>(
                    wbase + (size_t)(t * LPAD + j * 16 + c) * KPAD + ks * 32 + g * 8);
    };
    auto computeJ = [&](const short8 (&bf)[3][2]) {
#pragma unroll
        for (int mt = 0; mt < 4; mt++) {
            f32x4 a1 = {0.f, 0.f, 0.f, 0.f};
            f32x4 a2 = {0.f, 0.f, 0.f, 0.f};
            f32x4 a3 = {0.f, 0.f, 0.f, 0.f};
            a1 = __builtin_amdgcn_mfma_f32_16x16x32_bf16(af[mt][0], bf[0][0], a1, 0, 0, 0);
            a1 = __builtin_amdgcn_mfma_f32_16x16x32_bf16(af[mt][1], bf[0][1], a1, 0, 0, 0);
            a2 = __builtin_amdgcn_mfma_f32_16x16x32_bf16(af[mt][0], bf[1][0], a2, 0, 0, 0);
            a2 = __builtin_amdgcn_mfma_f32_16x16x32_bf16(af[mt][1], bf[1][1], a2, 0, 0, 0);
            a3 = __builtin_amdgcn_mfma_f32_16x16x32_bf16(af[mt][0], bf[2][0], a3, 0, 0, 0);
            a3 = __builtin_amdgcn_mfma_f32_16x16x32_bf16(af[mt][1], bf[2][1], a3, 0, 0, 0);
#pragma unroll
            for (int r = 0; r < 4; r++) {
                float m1 = a1[r], bb = a2[r], m2 = a3[r];
                float z = fmaf(xv[mt][r], m1, bb);
                float e = (z > 0.f) ? z : (__expf(z) - 1.0f);   // elu
                num[mt][r] = fmaf(e, m2, num[mt][r]);
                den[mt][r] += fmaxf(-m1 * m2, 0.f);             // relu
            }
        }
    };

    loadB(bfA, 0);
    loadB(bfB, 1);
    computeJ(bfA); loadB(bfA, 2);
    computeJ(bfB); loadB(bfB, 3);
    computeJ(bfA); loadB(bfA, 4);
    computeJ(bfB); loadB(bfB, 5);
    computeJ(bfA); loadB(bfA, 6);
    computeJ(bfB);
    computeJ(bfA);

#pragma unroll
    for (int mt = 0; mt < 4; mt++)
#pragma unroll
        for (int r = 0; r < 4; r++) {
            float n = num[mt][r], dn = den[mt][r];
#pragma unroll
            for (int mask = 1; mask < 16; mask <<= 1) {
                n  += __shfl_xor(n, mask);
                dn += __shfl_xor(dn, mask);
            }
            if (c == r) {
                int s = m0 + mt * 16 + g * 4 + r;
                int ti = d * NB + s;
                float y = tA[ti] * (xv[mt][r] + tS[ti] * __fdividef(n, dn + 1.0f)) + tB[ti];
                out[(size_t)s * 64 + out_off + d] = y;
            }
        }
}

extern "C" void kernel_launch(void* const* d_in, const int* in_sizes, int n_in,
                              void* d_out, int out_size, void* d_ws, size_t ws_size,
                              hipStream_t stream) {
    const float* x    = (const float*)d_in[0];
    const float* s1W1 = (const float*)d_in[1];
    const float* s1b1 = (const float*)d_in[2];
    const float* s1W2 = (const float*)d_in[3];
    const float* s1b2 = (const float*)d_in[4];
    const float* s2W1 = (const float*)d_in[5];
    const float* s2b1 = (const float*)d_in[6];
    const float* s2W2 = (const float*)d_in[7];
    const float* s2b2 = (const float*)d_in[8];
    float* out = (float*)d_out;

    char* ws = (char*)d_ws;
    unsigned short* W2R1 = (unsigned short*)ws;   ws += (size_t)NCR * KPAD * 2;
    unsigned short* W2R2 = (unsigned short*)ws;   ws += (size_t)NCR * KPAD * 2;
    unsigned short* hb1  = (unsigned short*)ws;   ws += (size_t)NB * KPAD * 2;
    unsigned short* hb2  = (unsigned short*)ws;   ws += (size_t)NB * KPAD * 2;
    float* xT            = (float*)ws;            ws += (size_t)64 * NB * 4;
    float* tB            = (float*)ws;            ws += (size_t)DIM * NB * 4;
    float* tS            = (float*)ws;            ws += (size_t)DIM * NB * 4;
    float* tA            = (float*)ws;

    // D1: prep both W2R + h1 (cond = x2) + x transpose
    combo_kernel<<<2 * PREPB + HB1B + XTB, 256, 0, stream>>>(
        s1W2, s1b2, W2R1, s2W2, s2b2, W2R2, x, s1W1, s1b1, hb1, xT);
    // D2: tail params subnet 1
    tail_kernel<<<DIM * NB / 256, 256, 0, stream>>>(hb1, W2R1, tB, tS, tA);
    // D3: y1 -> out cols 0..31
    y_mfma<<<dim3(NB / 256, DIM), 256, 0, stream>>>(xT, 0, hb1, W2R1, tB, tS, tA, out, 0);
    // D4: h2 (cond = y1)
    h_kernel<<<NB * 64 / 256, 256, 0, stream>>>(out, 0, s2W1, s2b1, hb2);
    // D5: tail params subnet 2
    tail_kernel<<<DIM * NB / 256, 256, 0, stream>>>(hb2, W2R2, tB, tS, tA);
    // D6: y2 -> out cols 32..63
    y_mfma<<<dim3(NB / 256, DIM), 256, 0, stream>>>(xT, DIM, hb2, W2R2, tB, tS, tA, out, DIM);
}

// Round 11
// 255.397 us; speedup vs baseline: 1.0243x; 1.0243x over previous
//
#include <hip/hip_runtime.h>
#include <hip/hip_bf16.h>

#define NB 16384
#define DIM 32
#define LS 100
#define KH 50
#define PCOLS 9696           // 3*DIM*LS + 3*DIM
#define LPAD 112             // LS padded to 7*16
#define DSTRIDE 352          // 3*LPAD + 16 tail slots (bias2, eps, alpha, 13 zero)
#define NCR (DIM * DSTRIDE)  // 11264 reordered columns
#define KPAD 64              // 50 real + 1 bias row + 13 zero
#define PREPB (NCR / 64)     // 176 prep blocks per subnet
#define HB1B (NB * 64 / 256) // 4096 h-blocks

typedef __attribute__((ext_vector_type(4))) float f32x4;
typedef __attribute__((ext_vector_type(8))) short short8;

static __device__ __forceinline__ unsigned short f2bf(float f) {
    __hip_bfloat16 h = __float2bfloat16(f);
    return *reinterpret_cast<unsigned short*>(&h);
}
static __device__ __forceinline__ float bf2f(unsigned short u) {
    __hip_bfloat16 h = *reinterpret_cast<__hip_bfloat16*>(&u);
    return __bfloat162float(h);
}

// ---- reorder + pad + bf16-ify W2 (b2 folded as k=50 row), linear k layout ----
// W2R[row][k], row = d*352 + q; q<336: q=t*112+l (orig col t*3200+d*100+l);
// q in 336..338: tail cols 9600/9632/9664 + d (bias2, eps, alpha); rest zero.
static __device__ __forceinline__ void prep_body(int bx, const float* __restrict__ W2,
                                                 const float* __restrict__ b2,
                                                 unsigned short* __restrict__ W2R,
                                                 unsigned short (&tile)[64][66]) {
    int cb = bx * 64;
    int tid = threadIdx.x;
    int cl = tid & 63;
    int kg = tid >> 6;
    int cp = cb + cl;
    int d = cp / DSTRIDE;
    int q = cp - d * DSTRIDE;
    int col;
    bool valid;
    if (q < 3 * LPAD) {
        int t = q / LPAD;
        int l = q - t * LPAD;
        col = t * (DIM * LS) + d * LS + l;
        valid = (l < LS);
    } else {
        int e = q - 3 * LPAD;
        col = 3 * DIM * LS + e * DIM + d;
        valid = (e < 3);
    }
#pragma unroll
    for (int kk = 0; kk < 16; kk++) {
        int k = kg * 16 + kk;
        float v = 0.0f;
        if (valid) {
            if (k < KH)       v = W2[(size_t)k * PCOLS + col];
            else if (k == KH) v = b2[col];
        }
        tile[cl][k] = f2bf(v);
    }
    __syncthreads();
    int k = tid & 63;
    int cg = tid >> 6;
#pragma unroll
    for (int ii = 0; ii < 16; ii++) {
        int lr = cg * 16 + ii;
        W2R[(size_t)(cb + lr) * KPAD + k] = tile[lr][k];
    }
}

// ---- h = relu(cond @ W1 + b1) -> bf16 [NB][64]; h[50]=1 (bias hook) ----
static __device__ __forceinline__ void h_body(int bx, const float* __restrict__ cond,
                                              int cond_off, const float* __restrict__ W1,
                                              const float* __restrict__ b1,
                                              unsigned short* __restrict__ hb) {
    int idx = bx * 256 + threadIdx.x;   // = s*64 + k; s is wave-uniform
    int s = idx >> 6, k = idx & 63;
    float v;
    if (k < KH) {
        const float* crow = cond + (size_t)s * 64 + cond_off;
        float acc = b1[k];
#pragma unroll
        for (int j = 0; j < DIM; j++) acc = fmaf(crow[j], W1[j * KH + k], acc);
        v = fmaxf(acc, 0.0f);
    } else {
        v = (k == KH) ? 1.0f : 0.0f;
    }
    hb[idx] = f2bf(v);
}

// ---- combined: prep both subnets' W2R + h1 (all independent) ----
__global__ __launch_bounds__(256) void combo_kernel(const float* __restrict__ W2a,
                                                    const float* __restrict__ b2a,
                                                    unsigned short* __restrict__ W2Ra,
                                                    const float* __restrict__ W2b,
                                                    const float* __restrict__ b2b,
                                                    unsigned short* __restrict__ W2Rb,
                                                    const float* __restrict__ x,
                                                    const float* __restrict__ W1,
                                                    const float* __restrict__ b1,
                                                    unsigned short* __restrict__ hb) {
    __shared__ unsigned short tile[64][66];
    int b = blockIdx.x;
    if (b < PREPB)          prep_body(b, W2a, b2a, W2Ra, tile);
    else if (b < 2 * PREPB) prep_body(b - PREPB, W2b, b2b, W2Rb, tile);
    else                    h_body(b - 2 * PREPB, x, DIM, W1, b1, hb);   // cond = x2
}

__global__ __launch_bounds__(256) void h_kernel(const float* __restrict__ cond, int cond_off,
                                                const float* __restrict__ W1,
                                                const float* __restrict__ b1,
                                                unsigned short* __restrict__ hb) {
    h_body(blockIdx.x, cond, cond_off, W1, b1, hb);
}

// ---- tail params from W2R's k-major tail rows (wave-uniform weights) ----
// thread t = d*NB + s; outputs [d][s]-coalesced.
__global__ __launch_bounds__(256) void tail_kernel(const unsigned short* __restrict__ hb,
                                                   const unsigned short* __restrict__ W2R,
                                                   float* __restrict__ tB,
                                                   float* __restrict__ tS,
                                                   float* __restrict__ tA) {
    int t = blockIdx.x * 256 + threadIdx.x;
    int d = t >> 14;            // NB = 16384
    int s = t & (NB - 1);
    const unsigned short* hrow = hb + (size_t)s * KPAD;
    const unsigned short* wb = W2R + ((size_t)d * DSTRIDE + 3 * LPAD) * KPAD;
    float pb = 0.f, pe = 0.f, pa = 0.f;
#pragma unroll
    for (int k = 0; k <= KH; k++) {      // k=50 carries b2 (h[50]=1)
        float hk = bf2f(hrow[k]);
        pb = fmaf(hk, bf2f(wb[k]), pb);
        pe = fmaf(hk, bf2f(wb[KPAD + k]), pe);
        pa = fmaf(hk, bf2f(wb[2 * KPAD + k]), pa);
    }
    int idx = d * NB + s;
    tB[idx] = pb;
    tS[idx] = 0.8f / (1.0f + __expf(-pe * 0.1f));
    tA[idx] = __expf(pa * 0.1f);
}

// ---- fused p-GEMM (MFMA, B from L2 w/ 2-deep reg prefetch) + PfndELU epilogue ----
// 256-thread block = 4 waves sharing one d; each wave: 64 samples (MT=4).
// Exact R3 register structure (108 VGPR): strided x reads, no xT, no tail MFMA.
__global__ __launch_bounds__(256) void y_mfma(const float* __restrict__ x, int x_off,
                                              const unsigned short* __restrict__ hb,
                                              const unsigned short* __restrict__ W2R,
                                              const float* __restrict__ tB,
                                              const float* __restrict__ tS,
                                              const float* __restrict__ tA,
                                              float* __restrict__ out, int out_off) {
    int tid = threadIdx.x;
    int lane = tid & 63, wave = tid >> 6;
    int c = lane & 15, g = lane >> 4;
    int d = blockIdx.y;
    int m0 = (blockIdx.x * 4 + wave) * 64;

    short8 af[4][2];
#pragma unroll
    for (int mt = 0; mt < 4; mt++)
#pragma unroll
        for (int ks = 0; ks < 2; ks++)
            af[mt][ks] = *reinterpret_cast<const short8*>(
                hb + (size_t)(m0 + mt * 16 + c) * KPAD + ks * 32 + g * 8);

    float xv[4][4];
#pragma unroll
    for (int mt = 0; mt < 4; mt++)
#pragma unroll
        for (int r = 0; r < 4; r++)
            xv[mt][r] = x[(size_t)(m0 + mt * 16 + g * 4 + r) * 64 + x_off + d];

    float num[4][4] = {};
    float den[4][4] = {};
    const unsigned short* wbase = W2R + (size_t)d * DSTRIDE * KPAD;

    short8 bfA[3][2], bfB[3][2];
    auto loadB = [&](short8 (&dst)[3][2], int j) {
#pragma unroll
        for (int t = 0; t < 3; t++)
#pragma unroll
            for (int ks = 0; ks < 2; ks++)
                dst[t][ks] = *reinterpret_cast<const short8*>(
                    wbase + (size_t)(t * LPAD + j * 16 + c) * KPAD + ks * 32 + g * 8);
    };
    auto computeJ = [&](const short8 (&bf)[3][2]) {
#pragma unroll
        for (int mt = 0; mt < 4; mt++) {
            f32x4 a1 = {0.f, 0.f, 0.f, 0.f};
            f32x4 a2 = {0.f, 0.f, 0.f, 0.f};
            f32x4 a3 = {0.f, 0.f, 0.f, 0.f};
            a1 = __builtin_amdgcn_mfma_f32_16x16x32_bf16(af[mt][0], bf[0][0], a1, 0, 0, 0);
            a1 = __builtin_amdgcn_mfma_f32_16x16x32_bf16(af[mt][1], bf[0][1], a1, 0, 0, 0);
            a2 = __builtin_amdgcn_mfma_f32_16x16x32_bf16(af[mt][0], bf[1][0], a2, 0, 0, 0);
            a2 = __builtin_amdgcn_mfma_f32_16x16x32_bf16(af[mt][1], bf[1][1], a2, 0, 0, 0);
            a3 = __builtin_amdgcn_mfma_f32_16x16x32_bf16(af[mt][0], bf[2][0], a3, 0, 0, 0);
            a3 = __builtin_amdgcn_mfma_f32_16x16x32_bf16(af[mt][1], bf[2][1], a3, 0, 0, 0);
#pragma unroll
            for (int r = 0; r < 4; r++) {
                float m1 = a1[r], bb = a2[r], m2 = a3[r];
                float z = fmaf(xv[mt][r], m1, bb);
                float e = (z > 0.f) ? z : (__expf(z) - 1.0f);   // elu
                num[mt][r] = fmaf(e, m2, num[mt][r]);
                den[mt][r] += fmaxf(-m1 * m2, 0.f);             // relu
            }
        }
    };

    loadB(bfA, 0);
    loadB(bfB, 1);
    computeJ(bfA); loadB(bfA, 2);
    computeJ(bfB); loadB(bfB, 3);
    computeJ(bfA); loadB(bfA, 4);
    computeJ(bfB); loadB(bfB, 5);
    computeJ(bfA); loadB(bfA, 6);
    computeJ(bfB);
    computeJ(bfA);

#pragma unroll
    for (int mt = 0; mt < 4; mt++)
#pragma unroll
        for (int r = 0; r < 4; r++) {
            float n = num[mt][r], dn = den[mt][r];
#pragma unroll
            for (int mask = 1; mask < 16; mask <<= 1) {
                n  += __shfl_xor(n, mask);
                dn += __shfl_xor(dn, mask);
            }
            if (c == r) {
                int s = m0 + mt * 16 + g * 4 + r;
                int ti = d * NB + s;
                float y = tA[ti] * (xv[mt][r] + tS[ti] * __fdividef(n, dn + 1.0f)) + tB[ti];
                out[(size_t)s * 64 + out_off + d] = y;
            }
        }
}

extern "C" void kernel_launch(void* const* d_in, const int* in_sizes, int n_in,
                              void* d_out, int out_size, void* d_ws, size_t ws_size,
                              hipStream_t stream) {
    const float* x    = (const float*)d_in[0];
    const float* s1W1 = (const float*)d_in[1];
    const float* s1b1 = (const float*)d_in[2];
    const float* s1W2 = (const float*)d_in[3];
    const float* s1b2 = (const float*)d_in[4];
    const float* s2W1 = (const float*)d_in[5];
    const float* s2b1 = (const float*)d_in[6];
    const float* s2W2 = (const float*)d_in[7];
    const float* s2b2 = (const float*)d_in[8];
    float* out = (float*)d_out;

    char* ws = (char*)d_ws;
    unsigned short* W2R1 = (unsigned short*)ws;   ws += (size_t)NCR * KPAD * 2;
    unsigned short* W2R2 = (unsigned short*)ws;   ws += (size_t)NCR * KPAD * 2;
    unsigned short* hb1  = (unsigned short*)ws;   ws += (size_t)NB * KPAD * 2;
    unsigned short* hb2  = (unsigned short*)ws;   ws += (size_t)NB * KPAD * 2;
    float* tB            = (float*)ws;            ws += (size_t)DIM * NB * 4;
    float* tS            = (float*)ws;            ws += (size_t)DIM * NB * 4;
    float* tA            = (float*)ws;

    // D1: prep both W2R + h1 (cond = x2)
    combo_kernel<<<2 * PREPB + HB1B, 256, 0, stream>>>(
        s1W2, s1b2, W2R1, s2W2, s2b2, W2R2, x, s1W1, s1b1, hb1);
    // D2: tail params subnet 1
    tail_kernel<<<DIM * NB / 256, 256, 0, stream>>>(hb1, W2R1, tB, tS, tA);
    // D3: y1 -> out cols 0..31
    y_mfma<<<dim3(NB / 256, DIM), 256, 0, stream>>>(x, 0, hb1, W2R1, tB, tS, tA, out, 0);
    // D4: h2 (cond = y1)
    h_kernel<<<NB * 64 / 256, 256, 0, stream>>>(out, 0, s2W1, s2b1, hb2);
    // D5: tail params subnet 2
    tail_kernel<<<DIM * NB / 256, 256, 0, stream>>>(hb2, W2R2, tB, tS, tA);
    // D6: y2 -> out cols 32..63
    y_mfma<<<dim3(NB / 256, DIM), 256, 0, stream>>>(x, DIM, hb2, W2R2, tB, tS, tA, out, DIM);
}

// Round 12
// 222.296 us; speedup vs baseline: 1.1768x; 1.1489x over previous
//
#include <hip/hip_runtime.h>
#include <hip/hip_bf16.h>

#define NB 16384
#define DIM 32
#define LS 100
#define KH 50
#define PCOLS 9696           // 3*DIM*LS + 3*DIM
#define LPAD 112             // LS padded to 7*16
#define DSTRIDE 352          // 3*LPAD + 16 tail slots (bias2, eps, alpha, 13 zero)
#define NCR (DIM * DSTRIDE)  // 11264 reordered columns
#define KPAD 64              // 50 real + 1 bias row + 13 zero
#define PREPB (NCR / 64)     // 176 prep blocks per subnet
#define HB1B (NB * 64 / 256) // 4096 h-blocks

typedef __attribute__((ext_vector_type(4))) float f32x4;
typedef __attribute__((ext_vector_type(8))) short short8;

static __device__ __forceinline__ unsigned short f2bf(float f) {
    __hip_bfloat16 h = __float2bfloat16(f);
    return *reinterpret_cast<unsigned short*>(&h);
}
static __device__ __forceinline__ float bf2f(unsigned short u) {
    __hip_bfloat16 h = *reinterpret_cast<__hip_bfloat16*>(&u);
    return __bfloat162float(h);
}

// ---- reorder + pad + bf16 + XOR-swizzle W2 (b2 folded as k=50 row) ----
// logical: W2R[row][k], row = d*352 + q; q<336: q=t*112+l (orig col
// t*3200+d*100+l); q 336..338: tail cols 9600/9632/9664 + d.
// stored k index swizzled: sk = k ^ ((row&7)<<3)  (matches y_mfma ds_read)
static __device__ __forceinline__ void prep_body(int bx, const float* __restrict__ W2,
                                                 const float* __restrict__ b2,
                                                 unsigned short* __restrict__ W2R,
                                                 unsigned short (&tile)[64][66]) {
    int cb = bx * 64;
    int tid = threadIdx.x;
    int cl = tid & 63;
    int kg = tid >> 6;
    int cp = cb + cl;
    int d = cp / DSTRIDE;
    int q = cp - d * DSTRIDE;
    int col;
    bool valid;
    if (q < 3 * LPAD) {
        int t = q / LPAD;
        int l = q - t * LPAD;
        col = t * (DIM * LS) + d * LS + l;
        valid = (l < LS);
    } else {
        int e = q - 3 * LPAD;
        col = 3 * DIM * LS + e * DIM + d;
        valid = (e < 3);
    }
#pragma unroll
    for (int kk = 0; kk < 16; kk++) {
        int k = kg * 16 + kk;
        float v = 0.0f;
        if (valid) {
            if (k < KH)       v = W2[(size_t)k * PCOLS + col];
            else if (k == KH) v = b2[col];
        }
        tile[cl][k] = f2bf(v);
    }
    __syncthreads();
    int k = tid & 63;
    int cg = tid >> 6;
#pragma unroll
    for (int ii = 0; ii < 16; ii++) {
        int lr = cg * 16 + ii;
        int row = cb + lr;
        W2R[(size_t)row * KPAD + (k ^ ((row & 7) << 3))] = tile[lr][k];
    }
}

// ---- h = relu(cond @ W1 + b1) -> bf16 [NB][64]; h[50]=1 (bias hook) ----
static __device__ __forceinline__ void h_body(int bx, const float* __restrict__ cond,
                                              int cond_off, const float* __restrict__ W1,
                                              const float* __restrict__ b1,
                                              unsigned short* __restrict__ hb) {
    int idx = bx * 256 + threadIdx.x;   // = s*64 + k; s is wave-uniform
    int s = idx >> 6, k = idx & 63;
    float v;
    if (k < KH) {
        const float* crow = cond + (size_t)s * 64 + cond_off;
        float acc = b1[k];
#pragma unroll
        for (int j = 0; j < DIM; j++) acc = fmaf(crow[j], W1[j * KH + k], acc);
        v = fmaxf(acc, 0.0f);
    } else {
        v = (k == KH) ? 1.0f : 0.0f;
    }
    hb[idx] = f2bf(v);
}

// ---- combined: prep both subnets' W2R + h1 (all independent) ----
__global__ __launch_bounds__(256) void combo_kernel(const float* __restrict__ W2a,
                                                    const float* __restrict__ b2a,
                                                    unsigned short* __restrict__ W2Ra,
                                                    const float* __restrict__ W2b,
                                                    const float* __restrict__ b2b,
                                                    unsigned short* __restrict__ W2Rb,
                                                    const float* __restrict__ x,
                                                    const float* __restrict__ W1,
                                                    const float* __restrict__ b1,
                                                    unsigned short* __restrict__ hb) {
    __shared__ unsigned short tile[64][66];
    int b = blockIdx.x;
    if (b < PREPB)          prep_body(b, W2a, b2a, W2Ra, tile);
    else if (b < 2 * PREPB) prep_body(b - PREPB, W2b, b2b, W2Rb, tile);
    else                    h_body(b - 2 * PREPB, x, DIM, W1, b1, hb);   // cond = x2
}

__global__ __launch_bounds__(256) void h_kernel(const float* __restrict__ cond, int cond_off,
                                                const float* __restrict__ W1,
                                                const float* __restrict__ b1,
                                                unsigned short* __restrict__ hb) {
    h_body(blockIdx.x, cond, cond_off, W1, b1, hb);
}

// ---- tail params from W2R's tail rows (336..338; swizzle-aware reads) ----
// thread t = d*NB + s; outputs [d][s]-coalesced.
__global__ __launch_bounds__(256) void tail_kernel(const unsigned short* __restrict__ hb,
                                                   const unsigned short* __restrict__ W2R,
                                                   float* __restrict__ tB,
                                                   float* __restrict__ tS,
                                                   float* __restrict__ tA) {
    int t = blockIdx.x * 256 + threadIdx.x;
    int d = t >> 14;            // NB = 16384
    int s = t & (NB - 1);
    const unsigned short* hrow = hb + (size_t)s * KPAD;
    const unsigned short* wb = W2R + ((size_t)d * DSTRIDE + 3 * LPAD) * KPAD;
    float pb = 0.f, pe = 0.f, pa = 0.f;
#pragma unroll
    for (int k = 0; k <= KH; k++) {      // k=50 carries b2 (h[50]=1)
        float hk = bf2f(hrow[k]);
        pb = fmaf(hk, bf2f(wb[k]), pb);                    // row 336: &7=0, no swizzle
        pe = fmaf(hk, bf2f(wb[KPAD + (k ^ 8)]), pe);       // row 337: &7=1
        pa = fmaf(hk, bf2f(wb[2 * KPAD + (k ^ 16)]), pa);  // row 338: &7=2
    }
    int idx = d * NB + s;
    tB[idx] = pb;
    tS[idx] = 0.8f / (1.0f + __expf(-pe * 0.1f));
    tA[idx] = __expf(pa * 0.1f);
}

// ---- fused p-GEMM: pipelined LDS chunks (6KB/j, 2-deep) + PfndELU epilogue ----
// 256-thread block = 4 waves sharing one d; each wave: 64 samples (MT=4).
// Barriers fence the schedule -> bounded live ranges (the R11 lesson).
__global__ __launch_bounds__(256) void y_mfma(const float* __restrict__ x, int x_off,
                                              const unsigned short* __restrict__ hb,
                                              const unsigned short* __restrict__ W2R,
                                              const float* __restrict__ tB,
                                              const float* __restrict__ tS,
                                              const float* __restrict__ tA,
                                              float* __restrict__ out, int out_off) {
    __shared__ unsigned short lB[2][3 * 16 * 64];   // 2 x 6144 B
    int tid = threadIdx.x;
    int lane = tid & 63, wave = tid >> 6;
    int c = lane & 15, g = lane >> 4;
    int d = blockIdx.y;
    int m0 = (blockIdx.x * 4 + wave) * 64;

    const char* src = (const char*)(W2R + (size_t)d * DSTRIDE * KPAD);

    // stage chunk j (3 streams x 16 rows x 128B, pre-swizzled) into buffer buf.
    // 6 x 1024B subchunks: wave w takes subchunk w; waves 0,1 also take 4,5.
    auto stage = [&](int buf, int j) {
        char* dstb = (char*)lB + buf * 6144;
        {
            int t = wave >> 1, half = wave & 1;
            __builtin_amdgcn_global_load_lds(
                (const __attribute__((address_space(1))) void*)
                    (src + (size_t)(t * LPAD + j * 16) * 128 + half * 1024 + lane * 16),
                (__attribute__((address_space(3))) void*)
                    (dstb + t * 2048 + half * 1024 + lane * 16),
                16, 0, 0);
        }
        if (wave < 2) {
            int half = wave;   // subchunk 4+wave -> t=2
            __builtin_amdgcn_global_load_lds(
                (const __attribute__((address_space(1))) void*)
                    (src + (size_t)(2 * LPAD + j * 16) * 128 + half * 1024 + lane * 16),
                (__attribute__((address_space(3))) void*)
                    (dstb + 2 * 2048 + half * 1024 + lane * 16),
                16, 0, 0);
        }
    };

    stage(0, 0);   // prologue

    // A fragments + x + per-sample tail params load (overlap first stage)
    short8 af[4][2];
#pragma unroll
    for (int mt = 0; mt < 4; mt++)
#pragma unroll
        for (int ks = 0; ks < 2; ks++)
            af[mt][ks] = *reinterpret_cast<const short8*>(
                hb + (size_t)(m0 + mt * 16 + c) * KPAD + ks * 32 + g * 8);

    float xv[4][4];
#pragma unroll
    for (int mt = 0; mt < 4; mt++)
#pragma unroll
        for (int r = 0; r < 4; r++)
            xv[mt][r] = x[(size_t)(m0 + mt * 16 + g * 4 + r) * 64 + x_off + d];

    float num[4][4] = {};
    float den[4][4] = {};

    for (int j = 0; j < 7; j++) {
        __syncthreads();                     // drains vmcnt -> chunk j resident
        if (j < 6) stage((j + 1) & 1, j + 1);

        const char* lb = (const char*)lB + (j & 1) * 6144;
        int sw = c & 7;
        short8 b00 = *reinterpret_cast<const short8*>(lb + 0 * 2048 + c * 128 + ((0 * 4 + g) ^ sw) * 16);
        short8 b01 = *reinterpret_cast<const short8*>(lb + 0 * 2048 + c * 128 + ((1 * 4 + g) ^ sw) * 16);
        short8 b10 = *reinterpret_cast<const short8*>(lb + 1 * 2048 + c * 128 + ((0 * 4 + g) ^ sw) * 16);
        short8 b11 = *reinterpret_cast<const short8*>(lb + 1 * 2048 + c * 128 + ((1 * 4 + g) ^ sw) * 16);
        short8 b20 = *reinterpret_cast<const short8*>(lb + 2 * 2048 + c * 128 + ((0 * 4 + g) ^ sw) * 16);
        short8 b21 = *reinterpret_cast<const short8*>(lb + 2 * 2048 + c * 128 + ((1 * 4 + g) ^ sw) * 16);

#pragma unroll
        for (int mt = 0; mt < 4; mt++) {
            f32x4 a1 = {0.f, 0.f, 0.f, 0.f};
            f32x4 a2 = {0.f, 0.f, 0.f, 0.f};
            f32x4 a3 = {0.f, 0.f, 0.f, 0.f};
            a1 = __builtin_amdgcn_mfma_f32_16x16x32_bf16(af[mt][0], b00, a1, 0, 0, 0);
            a1 = __builtin_amdgcn_mfma_f32_16x16x32_bf16(af[mt][1], b01, a1, 0, 0, 0);
            a2 = __builtin_amdgcn_mfma_f32_16x16x32_bf16(af[mt][0], b10, a2, 0, 0, 0);
            a2 = __builtin_amdgcn_mfma_f32_16x16x32_bf16(af[mt][1], b11, a2, 0, 0, 0);
            a3 = __builtin_amdgcn_mfma_f32_16x16x32_bf16(af[mt][0], b20, a3, 0, 0, 0);
            a3 = __builtin_amdgcn_mfma_f32_16x16x32_bf16(af[mt][1], b21, a3, 0, 0, 0);
#pragma unroll
            for (int r = 0; r < 4; r++) {
                float m1 = a1[r], bb = a2[r], m2 = a3[r];
                float z = fmaf(xv[mt][r], m1, bb);
                float e = (z > 0.f) ? z : (__expf(z) - 1.0f);   // elu
                num[mt][r] = fmaf(e, m2, num[mt][r]);
                den[mt][r] += fmaxf(-m1 * m2, 0.f);             // relu
            }
        }
    }

    // reduce num/den over the 16 l-lanes; writer lanes c==r
#pragma unroll
    for (int mt = 0; mt < 4; mt++)
#pragma unroll
        for (int r = 0; r < 4; r++) {
            float n = num[mt][r], dn = den[mt][r];
#pragma unroll
            for (int mask = 1; mask < 16; mask <<= 1) {
                n  += __shfl_xor(n, mask);
                dn += __shfl_xor(dn, mask);
            }
            if (c == r) {
                int s = m0 + mt * 16 + g * 4 + r;
                int ti = d * NB + s;
                float y = tA[ti] * (xv[mt][r] + tS[ti] * __fdividef(n, dn + 1.0f)) + tB[ti];
                out[(size_t)s * 64 + out_off + d] = y;
            }
        }
}

extern "C" void kernel_launch(void* const* d_in, const int* in_sizes, int n_in,
                              void* d_out, int out_size, void* d_ws, size_t ws_size,
                              hipStream_t stream) {
    const float* x    = (const float*)d_in[0];
    const float* s1W1 = (const float*)d_in[1];
    const float* s1b1 = (const float*)d_in[2];
    const float* s1W2 = (const float*)d_in[3];
    const float* s1b2 = (const float*)d_in[4];
    const float* s2W1 = (const float*)d_in[5];
    const float* s2b1 = (const float*)d_in[6];
    const float* s2W2 = (const float*)d_in[7];
    const float* s2b2 = (const float*)d_in[8];
    float* out = (float*)d_out;

    char* ws = (char*)d_ws;
    unsigned short* W2R1 = (unsigned short*)ws;   ws += (size_t)NCR * KPAD * 2;
    unsigned short* W2R2 = (unsigned short*)ws;   ws += (size_t)NCR * KPAD * 2;
    unsigned short* hb1  = (unsigned short*)ws;   ws += (size_t)NB * KPAD * 2;
    unsigned short* hb2  = (unsigned short*)ws;   ws += (size_t)NB * KPAD * 2;
    float* tB            = (float*)ws;            ws += (size_t)DIM * NB * 4;
    float* tS            = (float*)ws;            ws += (size_t)DIM * NB * 4;
    float* tA            = (float*)ws;

    // D1: prep both W2R (swizzled) + h1 (cond = x2)
    combo_kernel<<<2 * PREPB + HB1B, 256, 0, stream>>>(
        s1W2, s1b2, W2R1, s2W2, s2b2, W2R2, x, s1W1, s1b1, hb1);
    // D2: tail params subnet 1
    tail_kernel<<<DIM * NB / 256, 256, 0, stream>>>(hb1, W2R1, tB, tS, tA);
    // D3: y1 -> out cols 0..31
    y_mfma<<<dim3(NB / 256, DIM), 256, 0, stream>>>(x, 0, hb1, W2R1, tB, tS, tA, out, 0);
    // D4: h2 (cond = y1)
    h_kernel<<<NB * 64 / 256, 256, 0, stream>>>(out, 0, s2W1, s2b1, hb2);
    // D5: tail params subnet 2
    tail_kernel<<<DIM * NB / 256, 256, 0, stream>>>(hb2, W2R2, tB, tS, tA);
    // D6: y2 -> out cols 32..63
    y_mfma<<<dim3(NB / 256, DIM), 256, 0, stream>>>(x, DIM, hb2, W2R2, tB, tS, tA, out, DIM);
}